// Round 2
// baseline (976.906 us; speedup 1.0000x reference)
//
#include <hip/hip_runtime.h>
#include <stdint.h>

typedef unsigned short ushort_t;
typedef __attribute__((ext_vector_type(8))) short s8;    // 8 bf16 (4 VGPRs) — MFMA A/B frag
typedef __attribute__((ext_vector_type(4))) float f4;    // MFMA C/D frag / float4

#define LDK 72   // padded bf16 k-stride (144 B rows; 2-way bank alias = free on gfx950)

__device__ __forceinline__ float b2f(ushort_t u) {
    union { unsigned int i; float f; } c; c.i = ((unsigned int)u) << 16; return c.f;
}
__device__ __forceinline__ ushort_t f2b(float f) {
    union { float f; unsigned int i; } c; c.f = f;
    unsigned int b = c.i;
    b += 0x7FFFu + ((b >> 16) & 1u);   // RNE fp32 -> bf16
    return (ushort_t)(b >> 16);
}

// ---------------- node projections: Q,K,V = x @ {WQ,WK,WV} + bias (bf16 MFMA, fp32 in/acc) ----
__global__ __launch_bounds__(256) void node_proj_kernel(
    const float* __restrict__ x,
    const float* __restrict__ WQ, const float* __restrict__ bQ,
    const float* __restrict__ WK, const float* __restrict__ bK,
    const float* __restrict__ WV, const float* __restrict__ bV,
    ushort_t* __restrict__ Qt, ushort_t* __restrict__ Kt, ushort_t* __restrict__ Vt,
    int NN)
{
    __shared__ ushort_t sX[64 * LDK];
    __shared__ ushort_t sW[192 * LDK];   // W^T (bf16): rows = m*64 + out-col, k contiguous
    const int t = threadIdx.x;
    const int n0 = blockIdx.x * 64;

    // stage W^T with fp32->bf16 convert: sW[(m*64+n)*LDK + k] = bf16(W_m[k*64+n])
    {
        const float* Ws[3] = {WQ, WK, WV};
        int k  = t >> 3;          // 0..31
        int nc = (t & 7) * 8;     // 0..56
        for (int m = 0; m < 3; ++m) {
            #pragma unroll
            for (int rep = 0; rep < 2; ++rep) {
                int kk = k + rep * 32;
                f4 v0 = *(const f4*)(Ws[m] + kk * 64 + nc);
                f4 v1 = *(const f4*)(Ws[m] + kk * 64 + nc + 4);
                #pragma unroll
                for (int i = 0; i < 4; ++i) {
                    sW[(m * 64 + nc + i)     * LDK + kk] = f2b(v0[i]);
                    sW[(m * 64 + nc + 4 + i) * LDK + kk] = f2b(v1[i]);
                }
            }
        }
    }
    // stage x tile (64 rows, clamp tail rows), fp32 -> bf16
    {
        int r  = t >> 2;
        int c0 = (t & 3) * 16;
        int n = n0 + r; if (n >= NN) n = NN - 1;
        const float* src = x + (size_t)n * 64 + c0;
        ushort_t tmp[16];
        #pragma unroll
        for (int q = 0; q < 4; ++q) {
            f4 v = *(const f4*)(src + q * 4);
            #pragma unroll
            for (int i = 0; i < 4; ++i) tmp[q * 4 + i] = f2b(v[i]);
        }
        *(s8*)(&sX[r * LDK + c0])     = *(s8*)(tmp);
        *(s8*)(&sX[r * LDK + c0 + 8]) = *(s8*)(tmp + 8);
    }
    __syncthreads();

    const int w = t >> 6, l = t & 63, lr = l & 15, lq = l >> 4;

    // A frags: A[m=lane&15][k=quad*8+j], two k-steps of 32
    s8 a0 = *(const s8*)(&sX[(w * 16 + lr) * LDK + lq * 8]);
    s8 a1 = *(const s8*)(&sX[(w * 16 + lr) * LDK + 32 + lq * 8]);

    const float* bs[3]   = {bQ, bK, bV};
    ushort_t*    outs[3] = {Qt, Kt, Vt};

    #pragma unroll
    for (int ct = 0; ct < 12; ++ct) {
        int m  = ct >> 2;
        int cl = (ct & 3) * 16 + lr;           // col within matrix m
        s8 b0 = *(const s8*)(&sW[(ct * 16 + lr) * LDK + lq * 8]);
        s8 b1 = *(const s8*)(&sW[(ct * 16 + lr) * LDK + 32 + lq * 8]);
        float bias = bs[m][cl];
        f4 acc = {bias, bias, bias, bias};     // bias folded into C init (col-only dependence)
        acc = __builtin_amdgcn_mfma_f32_16x16x32_bf16(a0, b0, acc, 0, 0, 0);
        acc = __builtin_amdgcn_mfma_f32_16x16x32_bf16(a1, b1, acc, 0, 0, 0);
        ushort_t* outp = outs[m];
        #pragma unroll
        for (int r = 0; r < 4; ++r) {          // C/D: col=lane&15, row=quad*4+r
            int n = n0 + w * 16 + lq * 4 + r;
            if (n < NN) outp[(size_t)n * 64 + cl] = f2b(acc[r]);
        }
    }
}

// ---------------- edge kernel: E-proj (MFMA) + score + scatter ----------------
__global__ __launch_bounds__(256) void edge_kernel(
    const float* __restrict__ edge_attr,
    const int* __restrict__ edge_index,
    const float* __restrict__ WE, const float* __restrict__ bE,
    const ushort_t* __restrict__ Qt, const ushort_t* __restrict__ Kt,
    const ushort_t* __restrict__ Vt,
    float* __restrict__ wV, float* __restrict__ Z,
    int NE)
{
    __shared__ ushort_t sW[64 * LDK];
    __shared__ ushort_t sA[64 * LDK];
    __shared__ float    sE[64 * 65];   // fp32 E tile, +1 pad

    const int t  = threadIdx.x;
    const int e0 = blockIdx.x * 64;

    // stage WE^T (fp32 -> bf16)
    {
        int k  = t >> 3;
        int nc = (t & 7) * 8;
        #pragma unroll
        for (int rep = 0; rep < 2; ++rep) {
            int kk = k + rep * 32;
            f4 v0 = *(const f4*)(WE + kk * 64 + nc);
            f4 v1 = *(const f4*)(WE + kk * 64 + nc + 4);
            #pragma unroll
            for (int i = 0; i < 4; ++i) {
                sW[(nc + i)     * LDK + kk] = f2b(v0[i]);
                sW[(nc + 4 + i) * LDK + kk] = f2b(v1[i]);
            }
        }
    }
    // stage edge_attr tile (fp32 -> bf16)
    {
        int r  = t >> 2;
        int c0 = (t & 3) * 16;
        long e = e0 + r; if (e >= NE) e = NE - 1;
        const float* src = edge_attr + e * 64 + c0;
        ushort_t tmp[16];
        #pragma unroll
        for (int q = 0; q < 4; ++q) {
            f4 v = *(const f4*)(src + q * 4);
            #pragma unroll
            for (int i = 0; i < 4; ++i) tmp[q * 4 + i] = f2b(v[i]);
        }
        *(s8*)(&sA[r * LDK + c0])     = *(s8*)(tmp);
        *(s8*)(&sA[r * LDK + c0 + 8]) = *(s8*)(tmp + 8);
    }
    __syncthreads();

    const int w = t >> 6, l = t & 63, lr = l & 15, lq = l >> 4;

    s8 a0 = *(const s8*)(&sA[(w * 16 + lr) * LDK + lq * 8]);
    s8 a1 = *(const s8*)(&sA[(w * 16 + lr) * LDK + 32 + lq * 8]);

    #pragma unroll
    for (int ct = 0; ct < 4; ++ct) {
        s8 b0 = *(const s8*)(&sW[(ct * 16 + lr) * LDK + lq * 8]);
        s8 b1 = *(const s8*)(&sW[(ct * 16 + lr) * LDK + 32 + lq * 8]);
        float bias = bE[ct * 16 + lr];
        f4 acc = {bias, bias, bias, bias};
        acc = __builtin_amdgcn_mfma_f32_16x16x32_bf16(a0, b0, acc, 0, 0, 0);
        acc = __builtin_amdgcn_mfma_f32_16x16x32_bf16(a1, b1, acc, 0, 0, 0);
        #pragma unroll
        for (int r = 0; r < 4; ++r)
            sE[(w * 16 + lq * 4 + r) * 65 + ct * 16 + lr] = acc[r];   // E stays fp32
    }
    __syncthreads();

    const float inv_sqrt_d = 0.25f;   // 1/sqrt(16)
    const int j = l, h = l >> 4;

    for (int i = 0; i < 16; ++i) {
        int el = w * 16 + i;
        int e  = e0 + el;
        if (e >= NE) break;
        int src = edge_index[e];
        int dst = edge_index[NE + e];
        float p = b2f(Kt[src * 64 + j]) * b2f(Qt[dst * 64 + j]) * sE[el * 65 + j];
        // per-head (16-lane) reduce
        p += __shfl_xor(p, 1);
        p += __shfl_xor(p, 2);
        p += __shfl_xor(p, 4);
        p += __shfl_xor(p, 8);
        float s = p * inv_sqrt_d;
        s = fminf(fmaxf(s, -5.f), 5.f);
        float sc = __expf(s);
        float msg = b2f(Vt[src * 64 + j]) * sc;
        atomicAdd(&wV[dst * 64 + j], msg);
        if ((j & 15) == 0) atomicAdd(&Z[dst * 4 + h], sc);
    }
}

// ---------------- finalize: out = wV / (Z + 1e-6), fp32 ----------------
__global__ __launch_bounds__(256) void finalize_kernel(
    const float* __restrict__ wV, const float* __restrict__ Z,
    float* __restrict__ out, int NN)
{
    int idx = blockIdx.x * blockDim.x + threadIdx.x;   // one per 4 output elems
    int total = NN * 16;
    if (idx >= total) return;
    int n  = idx >> 4;
    int j0 = (idx & 15) * 4;                           // 4 cols, same head
    f4 v = *(const f4*)(wV + (size_t)n * 64 + j0);
    float z = Z[n * 4 + (j0 >> 4)];
    float inv = 1.f / (z + 1e-6f);
    f4 o;
    #pragma unroll
    for (int i = 0; i < 4; ++i) o[i] = v[i] * inv;
    *(f4*)(out + (size_t)n * 64 + j0) = o;
}

extern "C" void kernel_launch(void* const* d_in, const int* in_sizes, int n_in,
                              void* d_out, int out_size, void* d_ws, size_t ws_size,
                              hipStream_t stream)
{
    const float* x  = (const float*)d_in[0];
    const float* ea = (const float*)d_in[1];
    const int*   ei = (const int*)d_in[2];
    const float* WQ = (const float*)d_in[3];
    const float* bQ = (const float*)d_in[4];
    const float* WK = (const float*)d_in[5];
    const float* bK = (const float*)d_in[6];
    const float* WE = (const float*)d_in[7];
    const float* bE = (const float*)d_in[8];
    const float* WV = (const float*)d_in[9];
    const float* bV = (const float*)d_in[10];

    const int NN = in_sizes[0] / 64;
    const int NE = in_sizes[1] / 64;

    char* ws = (char*)d_ws;
    size_t off = 0;
    auto alloc = [&](size_t bytes) {
        void* p = ws + off;
        off = (off + bytes + 255) & ~(size_t)255;
        return p;
    };
    ushort_t* Qt  = (ushort_t*)alloc((size_t)NN * 64 * 2);
    ushort_t* Kt  = (ushort_t*)alloc((size_t)NN * 64 * 2);
    ushort_t* Vt  = (ushort_t*)alloc((size_t)NN * 64 * 2);
    float*    wVp = (float*)   alloc((size_t)NN * 64 * 4);
    float*    Zp  = (float*)   alloc((size_t)NN * 4 * 4);

    hipMemsetAsync(wVp, 0, (size_t)NN * 64 * 4, stream);
    hipMemsetAsync(Zp,  0, (size_t)NN * 4 * 4,  stream);

    node_proj_kernel<<<(NN + 63) / 64, 256, 0, stream>>>(
        x, WQ, bQ, WK, bK, WV, bV, Qt, Kt, Vt, NN);

    edge_kernel<<<(NE + 63) / 64, 256, 0, stream>>>(
        ea, ei, WE, bE, Qt, Kt, Vt, wVp, Zp, NE);

    finalize_kernel<<<(NN * 16 + 255) / 256, 256, 0, stream>>>(
        wVp, Zp, (float*)d_out, NN);
}